// Round 2
// baseline (2136.580 us; speedup 1.0000x reference)
//
#include <hip/hip_runtime.h>
#include <stdint.h>

// ---------------------------------------------------------------------------
// Model_3487513444700: 4-block gated-linear-recurrence LM, restructured from a
// sequential T-scan into per-block batched GEMMs + an associative h-scan.
// Shapes: NB=4, B=8, T=1024, D=1024, I=2816, V=256, M = B*T = 8192 rows.
// ---------------------------------------------------------------------------

#define NBLK 4
#define BB   8
#define TT   1024
#define DD   1024
#define II   2816
#define VV   256
#define MM   (BB * TT)     // 8192
#define CH   16            // scan chunks
#define TC   64            // steps per chunk (CH*TC == TT)

typedef float  f32x4 __attribute__((ext_vector_type(4)));
typedef short  s16x8 __attribute__((ext_vector_type(8)));

__device__ __forceinline__ ushort f2bf(float f) {
  uint32_t x = __builtin_bit_cast(uint32_t, f);
  uint32_t r = (x + 0x7fffu + ((x >> 16) & 1u)) >> 16;   // RNE
  return (ushort)r;
}
__device__ __forceinline__ float bf2f(ushort u) {
  uint32_t x = ((uint32_t)u) << 16;
  return __builtin_bit_cast(float, x);
}
__device__ __forceinline__ float sigm(float x) { return 1.f / (1.f + __expf(-x)); }

// block=256 helpers (4 waves). Leading __syncthreads protects s4 reuse.
__device__ __forceinline__ float block_sum(float v, float* s4) {
#pragma unroll
  for (int o = 32; o > 0; o >>= 1) v += __shfl_down(v, o);
  __syncthreads();
  if ((threadIdx.x & 63) == 0) s4[threadIdx.x >> 6] = v;
  __syncthreads();
  return s4[0] + s4[1] + s4[2] + s4[3];
}
__device__ __forceinline__ float block_max(float v, float* s4) {
#pragma unroll
  for (int o = 32; o > 0; o >>= 1) v = fmaxf(v, __shfl_down(v, o));
  __syncthreads();
  if ((threadIdx.x & 63) == 0) s4[threadIdx.x >> 6] = v;
  __syncthreads();
  return fmaxf(fmaxf(s4[0], s4[1]), fmaxf(s4[2], s4[3]));
}

__device__ __forceinline__ void mfma16(f32x4& d, s16x8 a, s16x8 b) {
  asm volatile("v_mfma_f32_16x16x32_bf16 %0, %1, %2, %0" : "+v"(d) : "v"(a), "v"(b));
}

#define GLL16(g, l)                                                            \
  __builtin_amdgcn_global_load_lds(                                            \
      (const __attribute__((address_space(1))) void*)(g),                      \
      (__attribute__((address_space(3))) void*)(l), 16, 0, 0)

// ---------------------------------------------------------------------------
// GEMM: C[M,N] = A[M,K](bf16) @ W[N,K]^T(bf16) + bias[N] (+ R[M,N]) -> f32/bf16
// 128x128 tile, BK=64, 4 waves (2x2 of 64x64), 16x16x32 bf16 MFMA.
// m97 2-barrier structure with width-16 global_load_lds staging.
// ---------------------------------------------------------------------------
template <bool HAS_RES, bool OUT_BF16>
__global__ __launch_bounds__(256) void gemm_bt(
    const ushort* __restrict__ A, const ushort* __restrict__ W,
    const float* __restrict__ bias, const float* __restrict__ R,
    void* __restrict__ Out, int M, int N, int K)
{
  __shared__ __align__(16) ushort As[128 * 64];
  __shared__ __align__(16) ushort Bs[128 * 64];
  const int tid  = threadIdx.x;
  const int lane = tid & 63;
  const int wid  = tid >> 6;
  const int wr = wid >> 1, wc = wid & 1;
  const int l15 = lane & 15, l4 = lane >> 4;
  const int m0 = blockIdx.y * 128, n0 = blockIdx.x * 128;

  f32x4 acc[4][4] = {};

  for (int k0 = 0; k0 < K; k0 += 64) {
    __syncthreads();                       // prev iter's LDS reads done
#pragma unroll
    for (int j = 0; j < 4; ++j) {
      const int flat = (j * 256 + tid) * 8;          // bf16 elem in [128][64] tile
      const int row = flat >> 6, col = flat & 63;
      GLL16(A + (size_t)(m0 + row) * K + (k0 + col), &As[(j * 256 + wid * 64) * 8]);
      GLL16(W + (size_t)(n0 + row) * K + (k0 + col), &Bs[(j * 256 + wid * 64) * 8]);
    }
    __syncthreads();                       // staging complete (vmcnt drained)
#pragma unroll
    for (int kk = 0; kk < 64; kk += 32) {
      s16x8 af[4], bf[4];
#pragma unroll
      for (int m = 0; m < 4; ++m)
        af[m] = *(const s16x8*)&As[(wr * 64 + m * 16 + l15) * 64 + kk + l4 * 8];
#pragma unroll
      for (int n = 0; n < 4; ++n)
        bf[n] = *(const s16x8*)&Bs[(wc * 64 + n * 16 + l15) * 64 + kk + l4 * 8];
#pragma unroll
      for (int m = 0; m < 4; ++m)
#pragma unroll
        for (int n = 0; n < 4; ++n)
          mfma16(acc[m][n], af[m], bf[n]);
    }
  }
  asm volatile("s_nop 7\n\ts_nop 7\n\ts_nop 7");   // MFMA->VALU hazard guard
#pragma unroll
  for (int n = 0; n < 4; ++n) {
    const int col = n0 + wc * 64 + n * 16 + l15;
    const float bv = bias[col];
#pragma unroll
    for (int m = 0; m < 4; ++m) {
      const int r0 = m0 + wr * 64 + m * 16 + l4 * 4;
#pragma unroll
      for (int i = 0; i < 4; ++i) {
        const size_t idx = (size_t)(r0 + i) * N + col;
        float v = acc[m][n][i] + bv;
        if (HAS_RES) v += R[idx];
        if (OUT_BF16) ((ushort*)Out)[idx] = f2bf(v);
        else          ((float*)Out)[idx]  = v;
      }
    }
  }
}

// ---------------------------------------------------------------------------
// Elementwise / rowwise kernels
// ---------------------------------------------------------------------------
__global__ void cast_f32_bf16(const float4* __restrict__ in, ushort4* __restrict__ out, int n4)
{
  const int stride = gridDim.x * blockDim.x;
  for (int i = blockIdx.x * blockDim.x + threadIdx.x; i < n4; i += stride) {
    const float4 v = in[i];
    ushort4 o; o.x = f2bf(v.x); o.y = f2bf(v.y); o.z = f2bf(v.z); o.w = f2bf(v.w);
    out[i] = o;
  }
}

__global__ void embed_kernel(const int* __restrict__ x, const float* __restrict__ emb,
                             float* __restrict__ y, int n4)
{
  const int stride = gridDim.x * blockDim.x;
  for (int i = blockIdx.x * blockDim.x + threadIdx.x; i < n4; i += stride) {
    const int r = i >> 8, d4 = i & 255;           // D/4 = 256 float4 per row
    const int tok = x[r];
    ((float4*)y)[i] = ((const float4*)emb)[(size_t)tok * 256 + d4];
  }
}

// lb[i] = cumsum(softmax(w_l[i])) - w_l[i][0]
__global__ __launch_bounds__(256) void lb_kernel(const float* __restrict__ wl, float* __restrict__ lb)
{
  __shared__ float sv[1024];
  __shared__ float s4[4];
  const int i = blockIdx.x, tid = threadIdx.x;
  const float* w = wl + (size_t)i * 1024;
  const float4 v = ((const float4*)w)[tid];
  float mx = fmaxf(fmaxf(v.x, v.y), fmaxf(v.z, v.w));
  mx = block_max(mx, s4);
  const float e0 = expf(v.x - mx), e1 = expf(v.y - mx), e2 = expf(v.z - mx), e3 = expf(v.w - mx);
  sv[tid * 4 + 0] = e0; sv[tid * 4 + 1] = e1; sv[tid * 4 + 2] = e2; sv[tid * 4 + 3] = e3;
  const float tot = block_sum(e0 + e1 + e2 + e3, s4);
  if (tid == 0) {
    float run = 0.f;
    for (int d = 0; d < 1024; ++d) { run += sv[d]; sv[d] = run; }
  }
  __syncthreads();
  const float w0 = w[0], inv = 1.f / tot;
#pragma unroll
  for (int k = 0; k < 4; ++k)
    lb[(size_t)i * 1024 + tid * 4 + k] = sv[tid * 4 + k] * inv - w0;
}

// xn = rms(y,w_in); a_{f,c,g} = bf16(rms(xn, w_{f,c,g}))
__global__ __launch_bounds__(256) void rms3_kernel(
    const float* __restrict__ y, const float* __restrict__ w_in,
    const float* __restrict__ w_f, const float* __restrict__ w_c, const float* __restrict__ w_g,
    ushort* __restrict__ af, ushort* __restrict__ ac, ushort* __restrict__ ag)
{
  __shared__ float s4[4];
  const int r = blockIdx.x, tid = threadIdx.x;
  const float4 v = ((const float4*)(y + (size_t)r * DD))[tid];
  float ss = v.x * v.x + v.y * v.y + v.z * v.z + v.w * v.w;
  ss = block_sum(ss, s4);
  const float rs = rsqrtf(ss * (1.f / DD) + 1e-6f);
  const float4 wi = ((const float4*)w_in)[tid];
  float4 xn;
  xn.x = v.x * rs * wi.x; xn.y = v.y * rs * wi.y; xn.z = v.z * rs * wi.z; xn.w = v.w * rs * wi.w;
  float ss2 = xn.x * xn.x + xn.y * xn.y + xn.z * xn.z + xn.w * xn.w;
  ss2 = block_sum(ss2, s4);
  const float rs2 = rsqrtf(ss2 * (1.f / DD) + 1e-6f);
  const float4 wf = ((const float4*)w_f)[tid];
  const float4 wc = ((const float4*)w_c)[tid];
  const float4 wg = ((const float4*)w_g)[tid];
  ushort4 o;
  const size_t ob = (size_t)r * 256 + tid;
  o.x = f2bf(xn.x * rs2 * wf.x); o.y = f2bf(xn.y * rs2 * wf.y);
  o.z = f2bf(xn.z * rs2 * wf.z); o.w = f2bf(xn.w * rs2 * wf.w);
  ((ushort4*)af)[ob] = o;
  o.x = f2bf(xn.x * rs2 * wc.x); o.y = f2bf(xn.y * rs2 * wc.y);
  o.z = f2bf(xn.z * rs2 * wc.z); o.w = f2bf(xn.w * rs2 * wc.w);
  ((ushort4*)ac)[ob] = o;
  o.x = f2bf(xn.x * rs2 * wg.x); o.y = f2bf(xn.y * rs2 * wg.y);
  o.z = f2bf(xn.z * rs2 * wg.z); o.w = f2bf(xn.w * rs2 * wg.w);
  ((ushort4*)ag)[ob] = o;
}

// ---- chunked linear scan: h_t = f_t h_{t-1} + (1-f_t) c_t ------------------
__global__ __launch_bounds__(256) void scan_passA(
    const float* __restrict__ rawf, const float* __restrict__ rawc,
    const float* __restrict__ lb, float* __restrict__ P, float* __restrict__ Q)
{
  const int idx = blockIdx.x * 256 + threadIdx.x;        // CH*BB*DD
  const int d = idx & 1023, b = (idx >> 10) & 7, c = idx >> 13;
  const float lbd = lb[d];
  size_t o = ((size_t)b * TT + c * TC) * DD + d;
  float p = 1.f, q = 0.f;
#pragma unroll 4
  for (int t = 0; t < TC; ++t) {
    const float f  = lbd + (1.f - lbd) * sigm(rawf[o]);
    const float xc = rawc[o];
    q = f * q + (1.f - f) * (xc * sigm(xc));
    p *= f;
    o += DD;
  }
  P[idx] = p; Q[idx] = q;
}

__global__ void scan_passB(const float* __restrict__ P, const float* __restrict__ Q,
                           float* __restrict__ Hin)
{
  const int idx = blockIdx.x * 256 + threadIdx.x;        // BB*DD
  float h = 0.f;
#pragma unroll
  for (int c = 0; c < CH; ++c) {
    Hin[c * (BB * DD) + idx] = h;
    h = P[c * (BB * DD) + idx] * h + Q[c * (BB * DD) + idx];
  }
}

__global__ __launch_bounds__(256) void scan_passC(
    const float* __restrict__ rawf, const float* __restrict__ rawc,
    const float* __restrict__ lb, const float* __restrict__ Hin, float* __restrict__ H)
{
  const int idx = blockIdx.x * 256 + threadIdx.x;
  const int d = idx & 1023, b = (idx >> 10) & 7, c = idx >> 13;
  const float lbd = lb[d];
  size_t o = ((size_t)b * TT + c * TC) * DD + d;
  float h = Hin[idx];
#pragma unroll 4
  for (int t = 0; t < TC; ++t) {
    const float f  = lbd + (1.f - lbd) * sigm(rawf[o]);
    const float xc = rawc[o];
    h = f * h + (1.f - f) * (xc * sigm(xc));
    H[o] = h;
    o += DD;
  }
}

// x_g = rms(g_raw, w_norm); a_o = bf16(rms(x_g * h * sigmoid(h), w_o))
__global__ __launch_bounds__(256) void gate_kernel(
    const float* __restrict__ graw, const float* __restrict__ H,
    const float* __restrict__ w_norm, const float* __restrict__ w_o,
    ushort* __restrict__ ao)
{
  __shared__ float s4[4];
  const int r = blockIdx.x, tid = threadIdx.x;
  const float4 g = ((const float4*)(graw + (size_t)r * DD))[tid];
  float ss = g.x * g.x + g.y * g.y + g.z * g.z + g.w * g.w;
  ss = block_sum(ss, s4);
  const float rs = rsqrtf(ss * (1.f / DD) + 1e-6f);
  const float4 wn = ((const float4*)w_norm)[tid];
  const float4 hv = ((const float4*)(H + (size_t)r * DD))[tid];
  float4 gt;
  gt.x = g.x * rs * wn.x * hv.x * sigm(hv.x);
  gt.y = g.y * rs * wn.y * hv.y * sigm(hv.y);
  gt.z = g.z * rs * wn.z * hv.z * sigm(hv.z);
  gt.w = g.w * rs * wn.w * hv.w * sigm(hv.w);
  float ss2 = gt.x * gt.x + gt.y * gt.y + gt.z * gt.z + gt.w * gt.w;
  ss2 = block_sum(ss2, s4);
  const float rs2 = rsqrtf(ss2 * (1.f / DD) + 1e-6f);
  const float4 wo = ((const float4*)w_o)[tid];
  ushort4 o;
  o.x = f2bf(gt.x * rs2 * wo.x); o.y = f2bf(gt.y * rs2 * wo.y);
  o.z = f2bf(gt.z * rs2 * wo.z); o.w = f2bf(gt.w * rs2 * wo.w);
  ((ushort4*)ao)[(size_t)r * 256 + tid] = o;
}

// a_u = bf16(rms(rms(x_o, w1), w2))
__global__ __launch_bounds__(256) void rms2_kernel(
    const float* __restrict__ xo, const float* __restrict__ w1,
    const float* __restrict__ w2, ushort* __restrict__ au)
{
  __shared__ float s4[4];
  const int r = blockIdx.x, tid = threadIdx.x;
  const float4 v = ((const float4*)(xo + (size_t)r * DD))[tid];
  float ss = v.x * v.x + v.y * v.y + v.z * v.z + v.w * v.w;
  ss = block_sum(ss, s4);
  const float rs = rsqrtf(ss * (1.f / DD) + 1e-6f);
  const float4 a = ((const float4*)w1)[tid];
  float4 t;
  t.x = v.x * rs * a.x; t.y = v.y * rs * a.y; t.z = v.z * rs * a.z; t.w = v.w * rs * a.w;
  float ss2 = t.x * t.x + t.y * t.y + t.z * t.z + t.w * t.w;
  ss2 = block_sum(ss2, s4);
  const float rs2 = rsqrtf(ss2 * (1.f / DD) + 1e-6f);
  const float4 b = ((const float4*)w2)[tid];
  ushort4 o;
  o.x = f2bf(t.x * rs2 * b.x); o.y = f2bf(t.y * rs2 * b.y);
  o.z = f2bf(t.z * rs2 * b.z); o.w = f2bf(t.w * rs2 * b.w);
  ((ushort4*)au)[(size_t)r * 256 + tid] = o;
}

// a_d = bf16(rms(silu(uu[:, :I]) * uu[:, I:], wd))   (uu stored bf16, 2I wide)
__global__ __launch_bounds__(256) void glu_kernel(
    const ushort* __restrict__ uu, const float* __restrict__ wd, ushort* __restrict__ ad)
{
  __shared__ float s4[4];
  const int r = blockIdx.x, tid = threadIdx.x;
  const ushort* u = uu + (size_t)r * (2 * II);
  float v[11];
  float ss = 0.f;
#pragma unroll
  for (int j = 0; j < 11; ++j) {
    const int d = tid + j * 256;
    const float u1 = bf2f(u[d]);
    const float u2 = bf2f(u[II + d]);
    const float s = u1 * sigm(u1) * u2;
    v[j] = s; ss += s * s;
  }
  ss = block_sum(ss, s4);
  const float rs = rsqrtf(ss * (1.f / II) + 1e-6f);
#pragma unroll
  for (int j = 0; j < 11; ++j) {
    const int d = tid + j * 256;
    ad[(size_t)r * II + d] = f2bf(v[j] * rs * wd[d]);
  }
}

// ---------------------------------------------------------------------------
extern "C" void kernel_launch(void* const* d_in, const int* in_sizes, int n_in,
                              void* d_out, int out_size, void* d_ws, size_t ws_size,
                              hipStream_t stream)
{
  const int*   x       = (const int*)  d_in[0];
  const float* emb     = (const float*)d_in[1];
  const float* wg_in   = (const float*)d_in[2];
  const float* wg_f    = (const float*)d_in[3];
  const float* wg_c    = (const float*)d_in[4];
  const float* wg_g    = (const float*)d_in[5];
  const float* wg_nm   = (const float*)d_in[6];
  const float* lf_w    = (const float*)d_in[7];
  const float* lf_b    = (const float*)d_in[8];
  const float* lc_w    = (const float*)d_in[9];
  const float* lc_b    = (const float*)d_in[10];
  const float* lg_w    = (const float*)d_in[11];
  const float* lg_b    = (const float*)d_in[12];
  const float* w_l     = (const float*)d_in[13];
  const float* wg_oo   = (const float*)d_in[14];
  const float* lo_w    = (const float*)d_in[15];
  const float* lo_b    = (const float*)d_in[16];
  const float* glu_wg  = (const float*)d_in[17];
  const float* glu_wgo = (const float*)d_in[18];
  const float* glu_wd  = (const float*)d_in[19];
  const float* lu_w    = (const float*)d_in[20];
  const float* lu_b    = (const float*)d_in[21];
  const float* ln_w    = (const float*)d_in[22];
  const float* ln_b    = (const float*)d_in[23];
  const float* out_w   = (const float*)d_in[24];
  const float* out_b   = (const float*)d_in[25];
  (void)in_sizes; (void)n_in; (void)out_size; (void)ws_size;

  char* ws = (char*)d_ws;
  size_t off = 0;
  auto alloc = [&](size_t bytes) -> char* {
    char* p = ws + off;
    off += (bytes + 255) & ~(size_t)255;
    return p;
  };

  // persistent bf16 weights
  ushort* Wlf = (ushort*)alloc((size_t)NBLK * DD * DD * 2);
  ushort* Wlc = (ushort*)alloc((size_t)NBLK * DD * DD * 2);
  ushort* Wlg = (ushort*)alloc((size_t)NBLK * DD * DD * 2);
  ushort* Wlo = (ushort*)alloc((size_t)NBLK * DD * DD * 2);
  ushort* Wlu = (ushort*)alloc((size_t)NBLK * 2 * II * DD * 2);
  ushort* Wln = (ushort*)alloc((size_t)NBLK * DD * II * 2);
  ushort* Wov = (ushort*)alloc((size_t)VV * DD * 2);
  float*  lbb = (float*)alloc((size_t)NBLK * DD * 4);
  // activations, each M*D*4 = 32 MB; 256B-aligned so consecutive allocs are
  // exactly contiguous. (rawf,rawc,H) contiguous: uu aliases over them.
  float* y    = (float*)alloc((size_t)MM * DD * 4);
  float* xo   = (float*)alloc((size_t)MM * DD * 4);
  float* rawf = (float*)alloc((size_t)MM * DD * 4);
  float* rawc = (float*)alloc((size_t)MM * DD * 4);
  float* H    = (float*)alloc((size_t)MM * DD * 4);
  float* rawg = (float*)alloc((size_t)MM * DD * 4);
  // (af,ac,ag) contiguous: ad aliases over them.
  ushort* af  = (ushort*)alloc((size_t)MM * DD * 2);
  ushort* ac  = (ushort*)alloc((size_t)MM * DD * 2);
  ushort* ag  = (ushort*)alloc((size_t)MM * DD * 2);
  float* P    = (float*)alloc((size_t)CH * BB * DD * 4);
  float* Q    = (float*)alloc((size_t)CH * BB * DD * 4);
  float* Hin  = (float*)alloc((size_t)CH * BB * DD * 4);
  // aliases (lifetimes disjoint):
  ushort* uu = (ushort*)rawf;   // [M, 2I] bf16 = 88 MB over rawf+rawc+H (96 MB)
  ushort* ao = af;              // gate output, dead before ad is written
  ushort* au = ac;              // glu input,  dead before ad is written
  ushort* ad = af;              // [M, I] bf16 = 44 MB over af+ac+ag (48 MB)
  ushort* ay = (ushort*)rawg;   // final cast of y

  auto cgrid = [](size_t n4) -> int {
    size_t g = (n4 + 255) / 256;
    return (int)(g < 2048 ? g : 2048);
  };

  // weight casts fp32 -> bf16
  cast_f32_bf16<<<cgrid((size_t)NBLK*DD*DD/4), 256, 0, stream>>>((const float4*)lf_w, (ushort4*)Wlf, NBLK*DD*DD/4);
  cast_f32_bf16<<<cgrid((size_t)NBLK*DD*DD/4), 256, 0, stream>>>((const float4*)lc_w, (ushort4*)Wlc, NBLK*DD*DD/4);
  cast_f32_bf16<<<cgrid((size_t)NBLK*DD*DD/4), 256, 0, stream>>>((const float4*)lg_w, (ushort4*)Wlg, NBLK*DD*DD/4);
  cast_f32_bf16<<<cgrid((size_t)NBLK*DD*DD/4), 256, 0, stream>>>((const float4*)lo_w, (ushort4*)Wlo, NBLK*DD*DD/4);
  cast_f32_bf16<<<cgrid((size_t)NBLK*2*II*DD/4), 256, 0, stream>>>((const float4*)lu_w, (ushort4*)Wlu, NBLK*2*II*DD/4);
  cast_f32_bf16<<<cgrid((size_t)NBLK*DD*II/4), 256, 0, stream>>>((const float4*)ln_w, (ushort4*)Wln, NBLK*DD*II/4);
  cast_f32_bf16<<<cgrid((size_t)VV*DD/4), 256, 0, stream>>>((const float4*)out_w, (ushort4*)Wov, VV*DD/4);

  lb_kernel<<<NBLK, 256, 0, stream>>>(w_l, lbb);
  embed_kernel<<<cgrid((size_t)MM*DD/4), 256, 0, stream>>>(x, emb, y, MM*DD/4);

  const dim3 gD(DD / 128, MM / 128);        // [8192 x 1024] outputs
  const dim3 gU(2 * II / 128, MM / 128);    // [8192 x 5632]
  const dim3 gV(VV / 128, MM / 128);        // [8192 x 256]

  for (int i = 0; i < NBLK; ++i) {
    const float* lbi = lbb + (size_t)i * DD;
    rms3_kernel<<<MM, 256, 0, stream>>>(y, wg_in + i*DD, wg_f + i*DD, wg_c + i*DD, wg_g + i*DD,
                                        af, ac, ag);
    gemm_bt<false,false><<<gD, 256, 0, stream>>>(af, Wlf + (size_t)i*DD*DD, lf_b + i*DD, nullptr, rawf, MM, DD, DD);
    gemm_bt<false,false><<<gD, 256, 0, stream>>>(ac, Wlc + (size_t)i*DD*DD, lc_b + i*DD, nullptr, rawc, MM, DD, DD);
    gemm_bt<false,false><<<gD, 256, 0, stream>>>(ag, Wlg + (size_t)i*DD*DD, lg_b + i*DD, nullptr, rawg, MM, DD, DD);
    scan_passA<<<CH*BB*DD/256, 256, 0, stream>>>(rawf, rawc, lbi, P, Q);
    scan_passB<<<BB*DD/256, 256, 0, stream>>>(P, Q, Hin);
    scan_passC<<<CH*BB*DD/256, 256, 0, stream>>>(rawf, rawc, lbi, Hin, H);
    gate_kernel<<<MM, 256, 0, stream>>>(rawg, H, wg_nm + i*DD, wg_oo + i*DD, ao);
    gemm_bt<true,false><<<gD, 256, 0, stream>>>(ao, Wlo + (size_t)i*DD*DD, lo_b + i*DD, y, xo, MM, DD, DD);
    rms2_kernel<<<MM, 256, 0, stream>>>(xo, glu_wg + i*DD, glu_wgo + i*DD, au);
    gemm_bt<false,true><<<gU, 256, 0, stream>>>(au, Wlu + (size_t)i*2*II*DD, lu_b + (size_t)i*2*II, nullptr, uu, MM, 2*II, DD);
    glu_kernel<<<MM, 256, 0, stream>>>(uu, glu_wd + (size_t)i*II, ad);
    gemm_bt<true,false><<<gD, 256, 0, stream>>>(ad, Wln + (size_t)i*DD*II, ln_b + i*DD, xo, y, MM, DD, II);
  }

  cast_f32_bf16<<<cgrid((size_t)MM*DD/4), 256, 0, stream>>>((const float4*)y, (ushort4*)ay, MM*DD/4);
  gemm_bt<false,false><<<gV, 256, 0, stream>>>(ay, Wov, out_b, nullptr, (float*)d_out, MM, VV, DD);
}